// Round 2
// baseline (4735.902 us; speedup 1.0000x reference)
//
#include <hip/hip_runtime.h>
#include <math.h>

using u32 = unsigned int;
using u64 = unsigned long long;

#define HF_ 38
#define WF_ 38
#define NPOS (HF_*WF_)        // 1444
#define NBATCH 2
#define M_ALL (NBATCH*NPOS)   // 2888
#define CIN_ 2048
#define CMID_ 512
#define NA 9
#define NANCH (NPOS*NA)       // 12996
#define SORTN 16384
#define PRE_NMS_ 6000
#define POST_NMS_ 1000
#define NWORDS 94             // ceil(6000/64)
#define NCH 105               // 21 cls + 84 bbox
#define NBIN 49
#define NMAP (NBIN*NCH)       // 5145
#define PADP 1600             // 40*40 padded spatial
#define IMGW_ 608.0

#define BM 64
#define BN 64
#define BK 16

// ---------------- zero fill (feat_p) ----------------
__global__ void k_fill0(float4* p, int n4) {
    int i = blockIdx.x * 256 + threadIdx.x;
    if (i < n4) p[i] = make_float4(0.f, 0.f, 0.f, 0.f);
}

// ---------------- features (B,C,H,W) -> padded (B,40,40,C) ----------------
__global__ void k_tfeat(const float* __restrict__ feat, float* __restrict__ feat_p) {
    __shared__ float t[32][33];
    int b = blockIdx.z;
    int pb = blockIdx.x * 32, cb = blockIdx.y * 32;
    int tx = threadIdx.x, ty = threadIdx.y;
    int p = pb + tx, c = cb + ty;
    if (p < NPOS) t[ty][tx] = feat[((size_t)b * CIN_ + c) * NPOS + p];
    __syncthreads();
    int p2 = pb + ty, c2 = cb + tx;
    if (p2 < NPOS) {
        int yy = p2 / WF_, xx = p2 % WF_;
        feat_p[((size_t)b * PADP + (yy + 1) * 40 + (xx + 1)) * CIN_ + c2] = t[tx][ty];
    }
}

// ---------------- w_rpn_conv (OC,C,3,3) -> w_t[tap][c][oc] ----------------
__global__ __launch_bounds__(256) void k_twrpn(const float* __restrict__ w, float* __restrict__ w_t) {
    __shared__ float t[64 * 145];
    int cb = blockIdx.x * 16;   // c tile of 16
    int ob = blockIdx.y * 64;   // oc tile of 64
    int tid = threadIdx.x;
#pragma unroll
    for (int j = 0; j < 9; ++j) {
        int fid = tid + j * 256;           // 0..2303 float4 loads
        int oc = fid / 36, q = fid % 36;
        float4 v = *(const float4*)(w + ((size_t)(ob + oc) * CIN_ + cb) * 9 + q * 4);
        t[oc * 145 + q * 4 + 0] = v.x;
        t[oc * 145 + q * 4 + 1] = v.y;
        t[oc * 145 + q * 4 + 2] = v.z;
        t[oc * 145 + q * 4 + 3] = v.w;
    }
    __syncthreads();
#pragma unroll
    for (int j = 0; j < 9; ++j) {
        int fid = tid + j * 256;
        int pair = fid >> 4, l16 = fid & 15;   // pair: 0..143 = c_local*9+tap
        int cl = pair / 9, tap = pair % 9;
        float4 v;
        v.x = t[(l16 * 4 + 0) * 145 + pair];
        v.y = t[(l16 * 4 + 1) * 145 + pair];
        v.z = t[(l16 * 4 + 2) * 145 + pair];
        v.w = t[(l16 * 4 + 3) * 145 + pair];
        *(float4*)(w_t + ((size_t)tap * CIN_ + cb + cl) * CMID_ + ob + l16 * 4) = v;
    }
}

// ---------------- combine w_obj + w_rpn_box -> W2d[45][512] (f64), bias2d[45] ----------------
__global__ void k_buildW2(const float* __restrict__ w_obj, const float* __restrict__ w_rbox,
                          const float* __restrict__ b_obj, const float* __restrict__ b_rbox,
                          double* __restrict__ W2d, double* __restrict__ bias2d) {
    int idx = blockIdx.x * 256 + threadIdx.x;
    if (idx < 45 * 512) {
        int n = idx >> 9, k = idx & 511;
        W2d[idx] = (double)((n < 9) ? w_obj[n * 512 + k] : w_rbox[(n - 9) * 512 + k]);
    }
    if (idx < 45) bias2d[idx] = (double)((idx < 9) ? b_obj[idx] : b_rbox[idx - 9]);
}

// ---------------- combined psroi bias: bias_c[bin*105+ch] ----------------
__global__ void k_buildbias(const float* __restrict__ b_cls, const float* __restrict__ b_bbox,
                            float* __restrict__ bias_c) {
    int n = blockIdx.x * 256 + threadIdx.x;
    if (n >= NMAP) return;
    int bin = n / NCH, ch = n % NCH;
    bias_c[n] = (ch < 21) ? b_cls[ch * NBIN + bin] : b_bbox[(ch - 21) * NBIN + bin];
}

// ---------------- RPN 3x3 conv as implicit GEMM, FP64 accumulation ----------------
__global__ __launch_bounds__(256) void k_conv(const float* __restrict__ feat_p,
                                              const float* __restrict__ w_t,
                                              const float* __restrict__ bias,
                                              double* __restrict__ rpn_d) {
    __shared__ float As[BK][BM + 4];
    __shared__ float Bs[BK][BN + 4];
    int m0 = blockIdx.x * BM, n0 = blockIdx.y * BN;
    int tid = threadIdx.x;
    int ty = tid >> 4, tx = tid & 15;
    int a_m = tid >> 2, a_k = (tid & 3) << 2;
    int b_k = tid >> 4, b_n = (tid & 15) << 2;
    int gm = m0 + a_m;
    bool mvalid = gm < M_ALL;
    int gms = mvalid ? gm : 0;
    int bb = gms / NPOS, p = gms % NPOS;
    int yy = p / WF_, xx = p % WF_;
    double acc[4][4] = {};
    for (int tap = 0; tap < 9; ++tap) {
        int dy = tap / 3 - 1, dx = tap % 3 - 1;
        const float* arow = feat_p + ((size_t)bb * PADP + (yy + dy + 1) * 40 + (xx + dx + 1)) * CIN_;
        const float* brow = w_t + ((size_t)tap * CIN_ + b_k) * CMID_ + n0 + b_n;
        for (int k0 = 0; k0 < CIN_; k0 += BK) {
            __syncthreads();
            float4 av = make_float4(0.f, 0.f, 0.f, 0.f);
            if (mvalid) av = *(const float4*)(arow + k0 + a_k);
            As[a_k + 0][a_m] = av.x;
            As[a_k + 1][a_m] = av.y;
            As[a_k + 2][a_m] = av.z;
            As[a_k + 3][a_m] = av.w;
            float4 bv = *(const float4*)(brow + (size_t)k0 * CMID_);
            *(float4*)&Bs[b_k][b_n] = bv;
            __syncthreads();
#pragma unroll
            for (int kk = 0; kk < BK; ++kk) {
                float4 a4 = *(const float4*)&As[kk][ty << 2];
                float4 b4 = *(const float4*)&Bs[kk][tx << 2];
                double ad[4] = {(double)a4.x, (double)a4.y, (double)a4.z, (double)a4.w};
                double bd[4] = {(double)b4.x, (double)b4.y, (double)b4.z, (double)b4.w};
#pragma unroll
                for (int i2 = 0; i2 < 4; ++i2)
#pragma unroll
                    for (int j2 = 0; j2 < 4; ++j2)
                        acc[i2][j2] += ad[i2] * bd[j2];
            }
        }
    }
#pragma unroll
    for (int i2 = 0; i2 < 4; ++i2) {
        int gmm = m0 + (ty << 2) + i2;
        if (gmm >= M_ALL) continue;
        int gn = n0 + (tx << 2);
#pragma unroll
        for (int j2 = 0; j2 < 4; ++j2) {
            double v = acc[i2][j2] + (double)bias[gn + j2];
            rpn_d[(size_t)gmm * CMID_ + gn + j2] = fmax(v, 0.0);
        }
    }
}

// ---------------- obj + deltas 1x1 (f64): od_d[m][45] ----------------
__global__ __launch_bounds__(64) void k_objdl(const double* __restrict__ rpn_d,
                                              const double* __restrict__ W2d,
                                              const double* __restrict__ bias2d,
                                              double* __restrict__ od_d) {
    __shared__ double s[512];
    int m = blockIdx.x;
    int tid = threadIdx.x;
    for (int i = tid; i < 512; i += 64) s[i] = rpn_d[(size_t)m * 512 + i];
    __syncthreads();
    if (tid < 45) {
        double acc = 0.0;
        for (int k = 0; k < 512; ++k) acc += s[k] * W2d[tid * 512 + k];
        od_d[(size_t)m * 45 + tid] = acc + bias2d[tid];
    }
}

// ---------------- decode boxes (f64 truth, f32 data semantics) + sort keys ----------------
__global__ void k_decode(const double* __restrict__ od_d, float4* __restrict__ boxes, u64* __restrict__ keys) {
    int g = blockIdx.x * 256 + threadIdx.x;
    if (g >= NBATCH * SORTN) return;
    int b = g / SORTN, i = g % SORTN;
    if (i >= NANCH) { keys[(size_t)b * SORTN + i] = ~0ull; return; }
    int p = i / NA, a = i % NA;
    int yy = p / WF_, xx = p % WF_;
    int ri = a / 3, si = a % 3;
    double sq = (ri == 0) ? 0.70710678118654757 : ((ri == 1) ? 1.0 : 1.4142135623730951);
    double size = 16.0 * (double)(8 << si);
    // anchor constants: reproduce reference f32 arithmetic bit-exactly (pure data, no noise)
    float wsa = (float)(size / sq);
    float hsa = (float)(size * sq);
    float cx = (xx + 0.5f) * 16.f, cy = (yy + 0.5f) * 16.f;
    float x1a = cx - 0.5f * wsa, x2a = cx + 0.5f * wsa;
    float y1a = cy - 0.5f * hsa, y2a = cy + 0.5f * hsa;
    float wa = x2a - x1a, ha = y2a - y1a;
    float cxa = x1a + 0.5f * wa, cya = y1a + 0.5f * ha;
    // noisy part in f64 (truth)
    const double* dptr = od_d + (size_t)(b * NPOS + p) * 45;
    double obj = dptr[a];
    double d0 = dptr[9 + a * 4 + 0], d1 = dptr[9 + a * 4 + 1];
    double d2 = dptr[9 + a * 4 + 2], d3 = dptr[9 + a * 4 + 3];
    double ncx = (double)cxa + d0 * (double)wa;
    double ncy = (double)cya + d1 * (double)ha;
    double nw = (double)wa * exp(fmin(fmax(d2, -4.0), 4.0));
    double nh = (double)ha * exp(fmin(fmax(d3, -4.0), 4.0));
    float x1 = (float)fmin(fmax(ncx - 0.5 * nw, 0.0), IMGW_);
    float y1 = (float)fmin(fmax(ncy - 0.5 * nh, 0.0), IMGW_);
    float x2 = (float)fmin(fmax(ncx + 0.5 * nw, 0.0), IMGW_);
    float y2 = (float)fmin(fmax(ncy + 0.5 * nh, 0.0), IMGW_);
    boxes[(size_t)b * NANCH + i] = make_float4(x1, y1, x2, y2);
    // min-size filter with f32 semantics (matches reference ops on f32 boxes)
    float w = x2 - x1, h = y2 - y1;
    float score = (w >= 16.f && h >= 16.f) ? (float)obj : -INFINITY;
    u32 f = __float_as_uint(score);
    u32 mk = (f & 0x80000000u) ? ~f : (f | 0x80000000u);  // ascending-order map
    u32 d = ~mk;                                          // descending
    keys[(size_t)b * SORTN + i] = ((u64)d << 32) | (u32)i;
}

// ---------------- single-block bitonic sort (per batch) over 16384 u64 keys ----------------
__global__ __launch_bounds__(1024) void k_sort(u64* __restrict__ keys) {
    u64* k = keys + (size_t)blockIdx.x * SORTN;
    for (int size = 2; size <= SORTN; size <<= 1) {
        for (int stride = size >> 1; stride > 0; stride >>= 1) {
            __syncthreads();
#pragma unroll
            for (int r = 0; r < 8; ++r) {
                int t = threadIdx.x + r * 1024;   // pair id 0..8191
                int i = ((t & ~(stride - 1)) << 1) | (t & (stride - 1));
                int j = i | stride;
                bool up = ((i & size) == 0);
                u64 a = k[i], b = k[j];
                if ((a > b) == up) { k[i] = b; k[j] = a; }
            }
        }
    }
}

// ---------------- gather top 6000 boxes in sorted order ----------------
__global__ void k_gather(const u64* __restrict__ keys, const float4* __restrict__ boxes,
                         float4* __restrict__ top) {
    int g = blockIdx.x * 256 + threadIdx.x;
    if (g >= NBATCH * PRE_NMS_) return;
    int b = g / PRE_NMS_, j = g % PRE_NMS_;
    u32 idx = (u32)keys[(size_t)b * SORTN + j];
    if (idx >= NANCH) idx = 0;   // only happens past the -inf limit; never consumed
    top[(size_t)b * PRE_NMS_ + j] = boxes[(size_t)b * NANCH + idx];
}

// ---------------- pairwise suppression bit matrix (f64 IoU, f32-rounded compare) ----------------
__global__ __launch_bounds__(256) void k_iou(const float4* __restrict__ top, u64* __restrict__ sup) {
    int wid = blockIdx.x * 4 + (threadIdx.x >> 6);
    int lane = threadIdx.x & 63;
    if (wid >= NBATCH * PRE_NMS_ * NWORDS) return;
    int b = wid / (PRE_NMS_ * NWORDS);
    int rem = wid % (PRE_NMS_ * NWORDS);
    int i = rem / NWORDS, wj = rem % NWORDS;
    const float4* tb = top + (size_t)b * PRE_NMS_;
    float4 bif = tb[i];
    double bix1 = bif.x, biy1 = bif.y, bix2 = bif.z, biy2 = bif.w;
    int j = wj * 64 + lane;
    bool s = false;
    if (j < PRE_NMS_) {
        float4 bjf = tb[j];
        double bjx1 = bjf.x, bjy1 = bjf.y, bjx2 = bjf.z, bjy2 = bjf.w;
        double xx1 = fmax(bix1, bjx1), yy1 = fmax(biy1, bjy1);
        double xx2 = fmin(bix2, bjx2), yy2 = fmin(biy2, bjy2);
        double inter = fmax(xx2 - xx1, 0.0) * fmax(yy2 - yy1, 0.0);
        double ai = (bix2 - bix1) * (biy2 - biy1);
        double aj = (bjx2 - bjx1) * (bjy2 - bjy1);
        double iou = inter / (ai + aj - inter + 1e-9);
        s = (float)iou > 0.7f;   // f32 comparison semantics of the reference
    }
    u64 mask = __ballot(s);
    if (lane == 0) sup[(size_t)wid] = mask;
}

// ---------------- sequential NMS scan (1 wave per batch, bitmask in registers) ----------------
__global__ void k_scan(const u64* __restrict__ keys, const float4* __restrict__ top,
                       const u64* __restrict__ sup, float4* __restrict__ props) {
    int b = blockIdx.x;
    int lane = threadIdx.x;
    const u64* kk = keys + (size_t)b * SORTN;
    const float4* tb = top + (size_t)b * PRE_NMS_;
    const u64* mat = sup + (size_t)b * PRE_NMS_ * NWORDS;
    float4* pr = props + (size_t)b * POST_NMS_;
    // first sorted position whose score is -inf (or 6000 if none)
    int lo = 0, hi = PRE_NMS_;
    while (lo < hi) {
        int mid = (lo + hi) >> 1;
        u32 khi = (u32)(kk[mid] >> 32);
        if (khi < 0xFF800000u) lo = mid + 1; else hi = mid;
    }
    int limit = lo;
    u64 r0 = 0, r1 = 0;
    int kept = 0;
    for (int i = 0; i < limit && kept < POST_NMS_; ++i) {
        int w = i >> 6, bit = i & 63;
        u64 word = (w < 64) ? __shfl(r0, w) : __shfl(r1, w - 64);
        if (!((word >> bit) & 1ull)) {
            if (lane == 0) pr[kept] = tb[i];
            const u64* row = mat + (size_t)i * NWORDS;
            r0 |= row[lane];
            int w1 = lane + 64;
            if (w1 < NWORDS) r1 |= row[w1];
            kept++;
        }
    }
    float4 pad = tb[0];
    for (int q = kept + lane; q < POST_NMS_; q += 64) pr[q] = pad;
}

// ---------------- psroi maps GEMM: maps[m][bin*105+ch] (fp32) ----------------
__global__ __launch_bounds__(256) void k_maps(const float* __restrict__ feat_p,
                                              const float* __restrict__ w_cls,
                                              const float* __restrict__ w_bbox,
                                              const float* __restrict__ bias_c,
                                              float* __restrict__ maps) {
    __shared__ float As[BK][BM + 4];
    __shared__ float Bs[BK][BN + 4];
    int m0 = blockIdx.x * BM, n0 = blockIdx.y * BN;
    int tid = threadIdx.x;
    int ty = tid >> 4, tx = tid & 15;
    int a_m = tid >> 2, a_k = (tid & 3) << 2;
    int gm = m0 + a_m;
    bool mvalid = gm < M_ALL;
    const float* arow;
    {
        int gms = mvalid ? gm : 0;
        int bb = gms / NPOS, p = gms % NPOS;
        int yy = p / WF_, xx = p % WF_;
        arow = feat_p + ((size_t)bb * PADP + (yy + 1) * 40 + (xx + 1)) * CIN_;
    }
    int w_n = tid >> 2, w_k = (tid & 3) << 2;
    int gnB = n0 + w_n;
    const float* brow = nullptr;
    if (gnB < NMAP) {
        int bin = gnB / NCH, ch = gnB % NCH;
        brow = (ch < 21) ? (w_cls + (size_t)(ch * NBIN + bin) * CIN_)
                         : (w_bbox + (size_t)((ch - 21) * NBIN + bin) * CIN_);
    }
    float acc[4][4] = {};
    for (int k0 = 0; k0 < CIN_; k0 += BK) {
        __syncthreads();
        float4 av = make_float4(0.f, 0.f, 0.f, 0.f);
        if (mvalid) av = *(const float4*)(arow + k0 + a_k);
        As[a_k + 0][a_m] = av.x;
        As[a_k + 1][a_m] = av.y;
        As[a_k + 2][a_m] = av.z;
        As[a_k + 3][a_m] = av.w;
        float4 bv = make_float4(0.f, 0.f, 0.f, 0.f);
        if (brow) bv = *(const float4*)(brow + k0 + w_k);
        Bs[w_k + 0][w_n] = bv.x;
        Bs[w_k + 1][w_n] = bv.y;
        Bs[w_k + 2][w_n] = bv.z;
        Bs[w_k + 3][w_n] = bv.w;
        __syncthreads();
#pragma unroll
        for (int kk = 0; kk < BK; ++kk) {
            float4 a4 = *(const float4*)&As[kk][ty << 2];
            float4 b4 = *(const float4*)&Bs[kk][tx << 2];
            float av2[4] = {a4.x, a4.y, a4.z, a4.w};
            float bv2[4] = {b4.x, b4.y, b4.z, b4.w};
#pragma unroll
            for (int i2 = 0; i2 < 4; ++i2)
#pragma unroll
                for (int j2 = 0; j2 < 4; ++j2)
                    acc[i2][j2] += av2[i2] * bv2[j2];
        }
    }
#pragma unroll
    for (int i2 = 0; i2 < 4; ++i2) {
        int gmm = m0 + (ty << 2) + i2;
        if (gmm >= M_ALL) continue;
#pragma unroll
        for (int j2 = 0; j2 < 4; ++j2) {
            int gnn = n0 + (tx << 2) + j2;
            if (gnn < NMAP) maps[(size_t)gmm * NMAP + gnn] = acc[i2][j2] + bias_c[gnn];
        }
    }
}

// ---------------- psroi align + mean ----------------
__global__ __launch_bounds__(128) void k_psroi(const float4* __restrict__ props,
                                               const float* __restrict__ maps,
                                               float* __restrict__ out) {
    __shared__ int so[4][196];
    __shared__ float sw[4][196];
    int r = blockIdx.x;
    int b = r / POST_NMS_;
    int tid = threadIdx.x;
    float4 box = props[r];
    float x1 = box.x * 0.0625f, y1 = box.y * 0.0625f;
    float bw = fmaxf(box.z * 0.0625f - x1, 1.f) / 7.f;
    float bh = fmaxf(box.w * 0.0625f - y1, 1.f) / 7.f;
    for (int s = tid; s < 196; s += 128) {
        int bin = s >> 2, sy = (s >> 1) & 1, sx = s & 1;
        int ph = bin / 7, pw = bin % 7;
        float gx = (float)pw + (sx ? 0.75f : 0.25f);
        float gy = (float)ph + (sy ? 0.75f : 0.25f);
        float px = fminf(fmaxf(x1 + gx * bw, 0.f), 37.f);
        float py = fminf(fmaxf(y1 + gy * bh, 0.f), 37.f);
        float x0f = floorf(px), y0f = floorf(py);
        float lx = px - x0f, ly = py - y0f;
        int x0 = (int)x0f, y0 = (int)y0f;
        int x1i = min(x0 + 1, 37), y1i = min(y0 + 1, 37);
        int base = b * NPOS;
        so[0][s] = (base + y0 * WF_ + x0) * NMAP + bin * NCH;
        so[1][s] = (base + y0 * WF_ + x1i) * NMAP + bin * NCH;
        so[2][s] = (base + y1i * WF_ + x0) * NMAP + bin * NCH;
        so[3][s] = (base + y1i * WF_ + x1i) * NMAP + bin * NCH;
        sw[0][s] = (1.f - ly) * (1.f - lx);
        sw[1][s] = (1.f - ly) * lx;
        sw[2][s] = ly * (1.f - lx);
        sw[3][s] = ly * lx;
    }
    __syncthreads();
    if (tid < NCH) {
        float acc = 0.f;
        for (int s = 0; s < 196; ++s) {
            acc += sw[0][s] * maps[(size_t)(so[0][s] + tid)]
                 + sw[1][s] * maps[(size_t)(so[1][s] + tid)]
                 + sw[2][s] * maps[(size_t)(so[2][s] + tid)]
                 + sw[3][s] * maps[(size_t)(so[3][s] + tid)];
        }
        out[(size_t)r * NCH + tid] = acc * 0.25f / 49.f;
    }
}

extern "C" void kernel_launch(void* const* d_in, const int* in_sizes, int n_in,
                              void* d_out, int out_size, void* d_ws, size_t ws_size,
                              hipStream_t stream) {
    (void)in_sizes; (void)n_in; (void)out_size; (void)ws_size;
    const float* features = (const float*)d_in[0];
    const float* w_rpn    = (const float*)d_in[1];
    const float* b_rpn    = (const float*)d_in[2];
    const float* w_obj    = (const float*)d_in[3];
    const float* b_obj    = (const float*)d_in[4];
    const float* w_rbox   = (const float*)d_in[5];
    const float* b_rbox   = (const float*)d_in[6];
    const float* w_cls    = (const float*)d_in[7];
    const float* b_cls    = (const float*)d_in[8];
    const float* w_bbox   = (const float*)d_in[9];
    const float* b_bbox   = (const float*)d_in[10];
    float* out = (float*)d_out;

    char* ws = (char*)d_ws;
    size_t off = 0;
    auto alloc = [&](size_t bytes) -> char* {
        char* p = ws + off;
        off += (bytes + 255) & ~(size_t)255;
        return p;
    };
    // persistent region
    float*  feat_p = (float*)alloc((size_t)NBATCH * PADP * CIN_ * 4);        // 26.2 MB
    float4* props  = (float4*)alloc((size_t)NBATCH * POST_NMS_ * 16);        // 32 KB
    float*  bias_c = (float*)alloc((size_t)NMAP * 4);                        // 21 KB
    // scratch region S — RPN pipeline lives here, then maps overlays it
    char* S = ws + off;
    size_t soff = 0;
    auto salloc = [&](size_t bytes) -> char* {
        char* p = S + soff;
        soff += (bytes + 255) & ~(size_t)255;
        return p;
    };
    float*  w_t    = (float*)salloc((size_t)9 * CIN_ * CMID_ * 4);           // 37.7 MB
    double* rpn_d  = (double*)salloc((size_t)M_ALL * CMID_ * 8);             // 11.8 MB
    double* W2d    = (double*)salloc((size_t)45 * 512 * 8);
    double* bias2d = (double*)salloc((size_t)45 * 8);
    double* od_d   = (double*)salloc((size_t)M_ALL * 45 * 8);                // 1.0 MB
    float4* boxes  = (float4*)salloc((size_t)NBATCH * NANCH * 16);           // 0.42 MB
    u64*    keys   = (u64*)salloc((size_t)NBATCH * SORTN * 8);               // 0.26 MB
    float4* top    = (float4*)salloc((size_t)NBATCH * PRE_NMS_ * 16);        // 0.19 MB
    u64*    sup    = (u64*)salloc((size_t)NBATCH * PRE_NMS_ * NWORDS * 8);   // 9.0 MB
    float*  maps   = (float*)S;   // overlay: 59.4 MB <= scratch total (~60.8 MB)
    // total ws usage ~ 87 MB

    int n4 = NBATCH * PADP * CIN_ / 4;
    k_fill0<<<(n4 + 255) / 256, 256, 0, stream>>>((float4*)feat_p, n4);
    k_tfeat<<<dim3((NPOS + 31) / 32, CIN_ / 32, NBATCH), dim3(32, 32), 0, stream>>>(features, feat_p);
    k_twrpn<<<dim3(CIN_ / 16, CMID_ / 64), 256, 0, stream>>>(w_rpn, w_t);
    k_buildW2<<<91, 256, 0, stream>>>(w_obj, w_rbox, b_obj, b_rbox, W2d, bias2d);
    k_buildbias<<<(NMAP + 255) / 256, 256, 0, stream>>>(b_cls, b_bbox, bias_c);
    k_conv<<<dim3((M_ALL + BM - 1) / BM, CMID_ / BN), 256, 0, stream>>>(feat_p, w_t, b_rpn, rpn_d);
    k_objdl<<<M_ALL, 64, 0, stream>>>(rpn_d, W2d, bias2d, od_d);
    k_decode<<<(NBATCH * SORTN) / 256, 256, 0, stream>>>(od_d, boxes, keys);
    k_sort<<<NBATCH, 1024, 0, stream>>>(keys);
    k_gather<<<(NBATCH * PRE_NMS_ + 255) / 256, 256, 0, stream>>>(keys, boxes, top);
    k_iou<<<(NBATCH * PRE_NMS_ * NWORDS + 3) / 4, 256, 0, stream>>>(top, sup);
    k_scan<<<NBATCH, 64, 0, stream>>>(keys, top, sup, props);
    k_maps<<<dim3((M_ALL + BM - 1) / BM, (NMAP + BN - 1) / BN), 256, 0, stream>>>(feat_p, w_cls, w_bbox, bias_c, maps);
    k_psroi<<<NBATCH * POST_NMS_, 128, 0, stream>>>(props, maps, out);
}

// Round 3
// 3680.470 us; speedup vs baseline: 1.2868x; 1.2868x over previous
//
#include <hip/hip_runtime.h>
#include <math.h>

using u32 = unsigned int;
using u64 = unsigned long long;

#define HF_ 38
#define WF_ 38
#define NPOS (HF_*WF_)        // 1444
#define NBATCH 2
#define M_ALL (NBATCH*NPOS)   // 2888
#define CIN_ 2048
#define CMID_ 512
#define NA 9
#define NANCH (NPOS*NA)       // 12996
#define SORTN 16384
#define PRE_NMS_ 6000
#define POST_NMS_ 1000
#define NWORDS 94             // ceil(6000/64)
#define NCH 105               // 21 cls + 84 bbox
#define NBIN 49
#define NMAP (NBIN*NCH)       // 5145
#define PADP 1600             // 40*40 padded spatial
#define IMGW_ 608.0

#define BM 64
#define BN 64
#define BK 16

// conv tiling
#define CBM 32
#define CBN 64
#define CBK 16

// ---------------- zero fill (feat_p) ----------------
__global__ void k_fill0(float4* p, int n4) {
    int i = blockIdx.x * 256 + threadIdx.x;
    if (i < n4) p[i] = make_float4(0.f, 0.f, 0.f, 0.f);
}

// ---------------- features (B,C,H,W) -> padded (B,40,40,C) ----------------
__global__ void k_tfeat(const float* __restrict__ feat, float* __restrict__ feat_p) {
    __shared__ float t[32][33];
    int b = blockIdx.z;
    int pb = blockIdx.x * 32, cb = blockIdx.y * 32;
    int tx = threadIdx.x, ty = threadIdx.y;
    int p = pb + tx, c = cb + ty;
    if (p < NPOS) t[ty][tx] = feat[((size_t)b * CIN_ + c) * NPOS + p];
    __syncthreads();
    int p2 = pb + ty, c2 = cb + tx;
    if (p2 < NPOS) {
        int yy = p2 / WF_, xx = p2 % WF_;
        feat_p[((size_t)b * PADP + (yy + 1) * 40 + (xx + 1)) * CIN_ + c2] = t[tx][ty];
    }
}

// ---------------- w_rpn_conv (OC,C,3,3) -> w_t[tap][c][oc] ----------------
__global__ __launch_bounds__(256) void k_twrpn(const float* __restrict__ w, float* __restrict__ w_t) {
    __shared__ float t[64 * 145];
    int cb = blockIdx.x * 16;   // c tile of 16
    int ob = blockIdx.y * 64;   // oc tile of 64
    int tid = threadIdx.x;
#pragma unroll
    for (int j = 0; j < 9; ++j) {
        int fid = tid + j * 256;           // 0..2303 float4 loads
        int oc = fid / 36, q = fid % 36;
        float4 v = *(const float4*)(w + ((size_t)(ob + oc) * CIN_ + cb) * 9 + q * 4);
        t[oc * 145 + q * 4 + 0] = v.x;
        t[oc * 145 + q * 4 + 1] = v.y;
        t[oc * 145 + q * 4 + 2] = v.z;
        t[oc * 145 + q * 4 + 3] = v.w;
    }
    __syncthreads();
#pragma unroll
    for (int j = 0; j < 9; ++j) {
        int fid = tid + j * 256;
        int pair = fid >> 4, l16 = fid & 15;   // pair: 0..143 = c_local*9+tap
        int cl = pair / 9, tap = pair % 9;
        float4 v;
        v.x = t[(l16 * 4 + 0) * 145 + pair];
        v.y = t[(l16 * 4 + 1) * 145 + pair];
        v.z = t[(l16 * 4 + 2) * 145 + pair];
        v.w = t[(l16 * 4 + 3) * 145 + pair];
        *(float4*)(w_t + ((size_t)tap * CIN_ + cb + cl) * CMID_ + ob + l16 * 4) = v;
    }
}

// ---------------- combine w_obj + w_rpn_box -> W2d[45][512] (f64), bias2d[45] ----------------
__global__ void k_buildW2(const float* __restrict__ w_obj, const float* __restrict__ w_rbox,
                          const float* __restrict__ b_obj, const float* __restrict__ b_rbox,
                          double* __restrict__ W2d, double* __restrict__ bias2d) {
    int idx = blockIdx.x * 256 + threadIdx.x;
    if (idx < 45 * 512) {
        int n = idx >> 9, k = idx & 511;
        W2d[idx] = (double)((n < 9) ? w_obj[n * 512 + k] : w_rbox[(n - 9) * 512 + k]);
    }
    if (idx < 45) bias2d[idx] = (double)((idx < 9) ? b_obj[idx] : b_rbox[idx - 9]);
}

// ---------------- combined psroi bias: bias_c[bin*105+ch] ----------------
__global__ void k_buildbias(const float* __restrict__ b_cls, const float* __restrict__ b_bbox,
                            float* __restrict__ bias_c) {
    int n = blockIdx.x * 256 + threadIdx.x;
    if (n >= NMAP) return;
    int bin = n / NCH, ch = n % NCH;
    bias_c[n] = (ch < 21) ? b_cls[ch * NBIN + bin] : b_bbox[(ch - 21) * NBIN + bin];
}

// ---------------- RPN 3x3 conv: f32 FMA inner, f64 fold every 4 BK tiles ----------------
__global__ __launch_bounds__(256) void k_conv(const float* __restrict__ feat_p,
                                              const float* __restrict__ w_t,
                                              const float* __restrict__ bias,
                                              float* __restrict__ rpn) {
    __shared__ float As[CBK][CBM + 4];
    __shared__ float Bs[CBK][CBN + 4];
    int m0 = blockIdx.x * CBM, n0 = blockIdx.y * CBN;
    int tid = threadIdx.x;
    int tx = tid & 15;         // col group -> cols 4*tx .. 4*tx+3
    int tyy = tid >> 4;        // 0..15 -> rows 2*tyy, 2*tyy+1
    int a_m = tid >> 3, a_k = (tid & 7) * 2;
    int b_k = tid >> 4, b_n = (tid & 15) * 4;
    int gm = m0 + a_m;
    bool mvalid = gm < M_ALL;
    int gms = mvalid ? gm : 0;
    int bb = gms / NPOS, p = gms % NPOS;
    int yy = p / WF_, xx = p % WF_;
    float acc[2][4] = {};
    double accd[2][4] = {};
    int tcount = 0;
    for (int tap = 0; tap < 9; ++tap) {
        int dy = tap / 3 - 1, dx = tap % 3 - 1;
        const float* arow = feat_p + ((size_t)bb * PADP + (yy + dy + 1) * 40 + (xx + dx + 1)) * CIN_;
        const float* brow = w_t + ((size_t)tap * CIN_ + b_k) * CMID_ + n0 + b_n;
        for (int k0 = 0; k0 < CIN_; k0 += CBK) {
            __syncthreads();
            float2 av = make_float2(0.f, 0.f);
            if (mvalid) av = *(const float2*)(arow + k0 + a_k);
            As[a_k + 0][a_m] = av.x;
            As[a_k + 1][a_m] = av.y;
            float4 bv = *(const float4*)(brow + (size_t)k0 * CMID_);
            *(float4*)&Bs[b_k][b_n] = bv;
            __syncthreads();
#pragma unroll
            for (int kk = 0; kk < CBK; ++kk) {
                float a0 = As[kk][tyy * 2 + 0];
                float a1 = As[kk][tyy * 2 + 1];
                float4 b4 = *(const float4*)&Bs[kk][tx * 4];
                acc[0][0] += a0 * b4.x; acc[0][1] += a0 * b4.y;
                acc[0][2] += a0 * b4.z; acc[0][3] += a0 * b4.w;
                acc[1][0] += a1 * b4.x; acc[1][1] += a1 * b4.y;
                acc[1][2] += a1 * b4.z; acc[1][3] += a1 * b4.w;
            }
            if ((++tcount & 3) == 0) {
#pragma unroll
                for (int i2 = 0; i2 < 2; ++i2)
#pragma unroll
                    for (int j2 = 0; j2 < 4; ++j2) {
                        accd[i2][j2] += (double)acc[i2][j2];
                        acc[i2][j2] = 0.f;
                    }
            }
        }
    }
#pragma unroll
    for (int i2 = 0; i2 < 2; ++i2)
#pragma unroll
        for (int j2 = 0; j2 < 4; ++j2) accd[i2][j2] += (double)acc[i2][j2];
#pragma unroll
    for (int i2 = 0; i2 < 2; ++i2) {
        int gmm = m0 + tyy * 2 + i2;
        if (gmm >= M_ALL) continue;
        int gn = n0 + tx * 4;
        float4 o;
        o.x = (float)fmax(accd[i2][0] + (double)bias[gn + 0], 0.0);
        o.y = (float)fmax(accd[i2][1] + (double)bias[gn + 1], 0.0);
        o.z = (float)fmax(accd[i2][2] + (double)bias[gn + 2], 0.0);
        o.w = (float)fmax(accd[i2][3] + (double)bias[gn + 3], 0.0);
        *(float4*)(rpn + (size_t)gmm * CMID_ + gn) = o;
    }
}

// ---------------- obj + deltas 1x1 (f64 accumulate from f32 rpn): od_d[m][45] ----------------
__global__ __launch_bounds__(64) void k_objdl(const float* __restrict__ rpn,
                                              const double* __restrict__ W2d,
                                              const double* __restrict__ bias2d,
                                              double* __restrict__ od_d) {
    __shared__ float s[512];
    int m = blockIdx.x;
    int tid = threadIdx.x;
    for (int i = tid; i < 512; i += 64) s[i] = rpn[(size_t)m * 512 + i];
    __syncthreads();
    if (tid < 45) {
        double acc = 0.0;
        for (int k = 0; k < 512; ++k) acc += (double)s[k] * W2d[tid * 512 + k];
        od_d[(size_t)m * 45 + tid] = acc + bias2d[tid];
    }
}

// ---------------- decode boxes (f64 truth, f32 data semantics) + sort keys ----------------
__global__ void k_decode(const double* __restrict__ od_d, float4* __restrict__ boxes, u64* __restrict__ keys) {
    int g = blockIdx.x * 256 + threadIdx.x;
    if (g >= NBATCH * SORTN) return;
    int b = g / SORTN, i = g % SORTN;
    if (i >= NANCH) { keys[(size_t)b * SORTN + i] = ~0ull; return; }
    int p = i / NA, a = i % NA;
    int yy = p / WF_, xx = p % WF_;
    int ri = a / 3, si = a % 3;
    double sq = (ri == 0) ? 0.70710678118654757 : ((ri == 1) ? 1.0 : 1.4142135623730951);
    double size = 16.0 * (double)(8 << si);
    // anchor constants: reproduce reference f32 arithmetic bit-exactly (pure data, no noise)
    float wsa = (float)(size / sq);
    float hsa = (float)(size * sq);
    float cx = (xx + 0.5f) * 16.f, cy = (yy + 0.5f) * 16.f;
    float x1a = cx - 0.5f * wsa, x2a = cx + 0.5f * wsa;
    float y1a = cy - 0.5f * hsa, y2a = cy + 0.5f * hsa;
    float wa = x2a - x1a, ha = y2a - y1a;
    float cxa = x1a + 0.5f * wa, cya = y1a + 0.5f * ha;
    // noisy part in f64 (truth)
    const double* dptr = od_d + (size_t)(b * NPOS + p) * 45;
    double obj = dptr[a];
    double d0 = dptr[9 + a * 4 + 0], d1 = dptr[9 + a * 4 + 1];
    double d2 = dptr[9 + a * 4 + 2], d3 = dptr[9 + a * 4 + 3];
    double ncx = (double)cxa + d0 * (double)wa;
    double ncy = (double)cya + d1 * (double)ha;
    double nw = (double)wa * exp(fmin(fmax(d2, -4.0), 4.0));
    double nh = (double)ha * exp(fmin(fmax(d3, -4.0), 4.0));
    float x1 = (float)fmin(fmax(ncx - 0.5 * nw, 0.0), IMGW_);
    float y1 = (float)fmin(fmax(ncy - 0.5 * nh, 0.0), IMGW_);
    float x2 = (float)fmin(fmax(ncx + 0.5 * nw, 0.0), IMGW_);
    float y2 = (float)fmin(fmax(ncy + 0.5 * nh, 0.0), IMGW_);
    boxes[(size_t)b * NANCH + i] = make_float4(x1, y1, x2, y2);
    // min-size filter with f32 semantics (matches reference ops on f32 boxes)
    float w = x2 - x1, h = y2 - y1;
    float score = (w >= 16.f && h >= 16.f) ? (float)obj : -INFINITY;
    u32 f = __float_as_uint(score);
    u32 mk = (f & 0x80000000u) ? ~f : (f | 0x80000000u);  // ascending-order map
    u32 d = ~mk;                                          // descending
    keys[(size_t)b * SORTN + i] = ((u64)d << 32) | (u32)i;
}

// ---------------- single-block bitonic sort (per batch) over 16384 u64 keys ----------------
__global__ __launch_bounds__(1024) void k_sort(u64* __restrict__ keys) {
    u64* k = keys + (size_t)blockIdx.x * SORTN;
    for (int size = 2; size <= SORTN; size <<= 1) {
        for (int stride = size >> 1; stride > 0; stride >>= 1) {
            __syncthreads();
#pragma unroll
            for (int r = 0; r < 8; ++r) {
                int t = threadIdx.x + r * 1024;   // pair id 0..8191
                int i = ((t & ~(stride - 1)) << 1) | (t & (stride - 1));
                int j = i | stride;
                bool up = ((i & size) == 0);
                u64 a = k[i], b = k[j];
                if ((a > b) == up) { k[i] = b; k[j] = a; }
            }
        }
    }
}

// ---------------- gather top 6000 boxes in sorted order ----------------
__global__ void k_gather(const u64* __restrict__ keys, const float4* __restrict__ boxes,
                         float4* __restrict__ top) {
    int g = blockIdx.x * 256 + threadIdx.x;
    if (g >= NBATCH * PRE_NMS_) return;
    int b = g / PRE_NMS_, j = g % PRE_NMS_;
    u32 idx = (u32)keys[(size_t)b * SORTN + j];
    if (idx >= NANCH) idx = 0;   // only happens past the -inf limit; never consumed
    top[(size_t)b * PRE_NMS_ + j] = boxes[(size_t)b * NANCH + idx];
}

// ---------------- pairwise suppression bit matrix (f32, reference op order) ----------------
__global__ __launch_bounds__(256) void k_iou(const float4* __restrict__ top, u64* __restrict__ sup) {
    int wid = blockIdx.x * 4 + (threadIdx.x >> 6);
    int lane = threadIdx.x & 63;
    if (wid >= NBATCH * PRE_NMS_ * NWORDS) return;
    int b = wid / (PRE_NMS_ * NWORDS);
    int rem = wid % (PRE_NMS_ * NWORDS);
    int i = rem / NWORDS, wj = rem % NWORDS;
    const float4* tb = top + (size_t)b * PRE_NMS_;
    float4 bi = tb[i];
    int j = wj * 64 + lane;
    bool s = false;
    if (j < PRE_NMS_) {
        float4 bj = tb[j];
        float xx1 = fmaxf(bi.x, bj.x), yy1 = fmaxf(bi.y, bj.y);
        float xx2 = fminf(bi.z, bj.z), yy2 = fminf(bi.w, bj.w);
        float inter = fmaxf(xx2 - xx1, 0.f) * fmaxf(yy2 - yy1, 0.f);
        float ai = (bi.z - bi.x) * (bi.w - bi.y);
        float aj = (bj.z - bj.x) * (bj.w - bj.y);
        float iou = inter / (ai + aj - inter + 1e-9f);
        s = iou > 0.7f;
    }
    u64 mask = __ballot(s);
    if (lane == 0) sup[(size_t)wid] = mask;
}

// ---------------- sequential NMS scan (1 wave per batch, bitmask in registers) ----------------
__global__ void k_scan(const u64* __restrict__ keys, const float4* __restrict__ top,
                       const u64* __restrict__ sup, float4* __restrict__ props) {
    int b = blockIdx.x;
    int lane = threadIdx.x;
    const u64* kk = keys + (size_t)b * SORTN;
    const float4* tb = top + (size_t)b * PRE_NMS_;
    const u64* mat = sup + (size_t)b * PRE_NMS_ * NWORDS;
    float4* pr = props + (size_t)b * POST_NMS_;
    // first sorted position whose score is -inf (or 6000 if none)
    int lo = 0, hi = PRE_NMS_;
    while (lo < hi) {
        int mid = (lo + hi) >> 1;
        u32 khi = (u32)(kk[mid] >> 32);
        if (khi < 0xFF800000u) lo = mid + 1; else hi = mid;
    }
    int limit = lo;
    u64 r0 = 0, r1 = 0;
    int kept = 0;
    for (int i = 0; i < limit && kept < POST_NMS_; ++i) {
        int w = i >> 6, bit = i & 63;
        u64 word = (w < 64) ? __shfl(r0, w) : __shfl(r1, w - 64);
        if (!((word >> bit) & 1ull)) {
            if (lane == 0) pr[kept] = tb[i];
            const u64* row = mat + (size_t)i * NWORDS;
            r0 |= row[lane];
            int w1 = lane + 64;
            if (w1 < NWORDS) r1 |= row[w1];
            kept++;
        }
    }
    float4 pad = tb[0];
    for (int q = kept + lane; q < POST_NMS_; q += 64) pr[q] = pad;
}

// ---------------- psroi maps GEMM: maps[m][bin*105+ch] (fp32) ----------------
__global__ __launch_bounds__(256) void k_maps(const float* __restrict__ feat_p,
                                              const float* __restrict__ w_cls,
                                              const float* __restrict__ w_bbox,
                                              const float* __restrict__ bias_c,
                                              float* __restrict__ maps) {
    __shared__ float As[BK][BM + 4];
    __shared__ float Bs[BK][BN + 4];
    int m0 = blockIdx.x * BM, n0 = blockIdx.y * BN;
    int tid = threadIdx.x;
    int ty = tid >> 4, tx = tid & 15;
    int a_m = tid >> 2, a_k = (tid & 3) << 2;
    int gm = m0 + a_m;
    bool mvalid = gm < M_ALL;
    const float* arow;
    {
        int gms = mvalid ? gm : 0;
        int bb = gms / NPOS, p = gms % NPOS;
        int yy = p / WF_, xx = p % WF_;
        arow = feat_p + ((size_t)bb * PADP + (yy + 1) * 40 + (xx + 1)) * CIN_;
    }
    int w_n = tid >> 2, w_k = (tid & 3) << 2;
    int gnB = n0 + w_n;
    const float* brow = nullptr;
    if (gnB < NMAP) {
        int bin = gnB / NCH, ch = gnB % NCH;
        brow = (ch < 21) ? (w_cls + (size_t)(ch * NBIN + bin) * CIN_)
                         : (w_bbox + (size_t)((ch - 21) * NBIN + bin) * CIN_);
    }
    float acc[4][4] = {};
    for (int k0 = 0; k0 < CIN_; k0 += BK) {
        __syncthreads();
        float4 av = make_float4(0.f, 0.f, 0.f, 0.f);
        if (mvalid) av = *(const float4*)(arow + k0 + a_k);
        As[a_k + 0][a_m] = av.x;
        As[a_k + 1][a_m] = av.y;
        As[a_k + 2][a_m] = av.z;
        As[a_k + 3][a_m] = av.w;
        float4 bv = make_float4(0.f, 0.f, 0.f, 0.f);
        if (brow) bv = *(const float4*)(brow + k0 + w_k);
        Bs[w_k + 0][w_n] = bv.x;
        Bs[w_k + 1][w_n] = bv.y;
        Bs[w_k + 2][w_n] = bv.z;
        Bs[w_k + 3][w_n] = bv.w;
        __syncthreads();
#pragma unroll
        for (int kk = 0; kk < BK; ++kk) {
            float4 a4 = *(const float4*)&As[kk][ty << 2];
            float4 b4 = *(const float4*)&Bs[kk][tx << 2];
            float av2[4] = {a4.x, a4.y, a4.z, a4.w};
            float bv2[4] = {b4.x, b4.y, b4.z, b4.w};
#pragma unroll
            for (int i2 = 0; i2 < 4; ++i2)
#pragma unroll
                for (int j2 = 0; j2 < 4; ++j2)
                    acc[i2][j2] += av2[i2] * bv2[j2];
        }
    }
#pragma unroll
    for (int i2 = 0; i2 < 4; ++i2) {
        int gmm = m0 + (ty << 2) + i2;
        if (gmm >= M_ALL) continue;
#pragma unroll
        for (int j2 = 0; j2 < 4; ++j2) {
            int gnn = n0 + (tx << 2) + j2;
            if (gnn < NMAP) maps[(size_t)gmm * NMAP + gnn] = acc[i2][j2] + bias_c[gnn];
        }
    }
}

// ---------------- psroi align + mean ----------------
__global__ __launch_bounds__(128) void k_psroi(const float4* __restrict__ props,
                                               const float* __restrict__ maps,
                                               float* __restrict__ out) {
    __shared__ int so[4][196];
    __shared__ float sw[4][196];
    int r = blockIdx.x;
    int b = r / POST_NMS_;
    int tid = threadIdx.x;
    float4 box = props[r];
    float x1 = box.x * 0.0625f, y1 = box.y * 0.0625f;
    float bw = fmaxf(box.z * 0.0625f - x1, 1.f) / 7.f;
    float bh = fmaxf(box.w * 0.0625f - y1, 1.f) / 7.f;
    for (int s = tid; s < 196; s += 128) {
        int bin = s >> 2, sy = (s >> 1) & 1, sx = s & 1;
        int ph = bin / 7, pw = bin % 7;
        float gx = (float)pw + (sx ? 0.75f : 0.25f);
        float gy = (float)ph + (sy ? 0.75f : 0.25f);
        float px = fminf(fmaxf(x1 + gx * bw, 0.f), 37.f);
        float py = fminf(fmaxf(y1 + gy * bh, 0.f), 37.f);
        float x0f = floorf(px), y0f = floorf(py);
        float lx = px - x0f, ly = py - y0f;
        int x0 = (int)x0f, y0 = (int)y0f;
        int x1i = min(x0 + 1, 37), y1i = min(y0 + 1, 37);
        int base = b * NPOS;
        so[0][s] = (base + y0 * WF_ + x0) * NMAP + bin * NCH;
        so[1][s] = (base + y0 * WF_ + x1i) * NMAP + bin * NCH;
        so[2][s] = (base + y1i * WF_ + x0) * NMAP + bin * NCH;
        so[3][s] = (base + y1i * WF_ + x1i) * NMAP + bin * NCH;
        sw[0][s] = (1.f - ly) * (1.f - lx);
        sw[1][s] = (1.f - ly) * lx;
        sw[2][s] = ly * (1.f - lx);
        sw[3][s] = ly * lx;
    }
    __syncthreads();
    if (tid < NCH) {
        float acc = 0.f;
        for (int s = 0; s < 196; ++s) {
            acc += sw[0][s] * maps[(size_t)(so[0][s] + tid)]
                 + sw[1][s] * maps[(size_t)(so[1][s] + tid)]
                 + sw[2][s] * maps[(size_t)(so[2][s] + tid)]
                 + sw[3][s] * maps[(size_t)(so[3][s] + tid)];
        }
        out[(size_t)r * NCH + tid] = acc * 0.25f / 49.f;
    }
}

extern "C" void kernel_launch(void* const* d_in, const int* in_sizes, int n_in,
                              void* d_out, int out_size, void* d_ws, size_t ws_size,
                              hipStream_t stream) {
    (void)in_sizes; (void)n_in; (void)out_size; (void)ws_size;
    const float* features = (const float*)d_in[0];
    const float* w_rpn    = (const float*)d_in[1];
    const float* b_rpn    = (const float*)d_in[2];
    const float* w_obj    = (const float*)d_in[3];
    const float* b_obj    = (const float*)d_in[4];
    const float* w_rbox   = (const float*)d_in[5];
    const float* b_rbox   = (const float*)d_in[6];
    const float* w_cls    = (const float*)d_in[7];
    const float* b_cls    = (const float*)d_in[8];
    const float* w_bbox   = (const float*)d_in[9];
    const float* b_bbox   = (const float*)d_in[10];
    float* out = (float*)d_out;

    char* ws = (char*)d_ws;
    size_t off = 0;
    auto alloc = [&](size_t bytes) -> char* {
        char* p = ws + off;
        off += (bytes + 255) & ~(size_t)255;
        return p;
    };
    // persistent region
    float*  feat_p = (float*)alloc((size_t)NBATCH * PADP * CIN_ * 4);        // 26.2 MB
    float4* props  = (float4*)alloc((size_t)NBATCH * POST_NMS_ * 16);        // 32 KB
    float*  bias_c = (float*)alloc((size_t)NMAP * 4);                        // 21 KB
    // scratch region S — RPN pipeline lives here, then maps overlays it
    char* S = ws + off;
    size_t soff = 0;
    auto salloc = [&](size_t bytes) -> char* {
        char* p = S + soff;
        soff += (bytes + 255) & ~(size_t)255;
        return p;
    };
    float*  w_t    = (float*)salloc((size_t)9 * CIN_ * CMID_ * 4);           // 37.7 MB
    float*  rpn    = (float*)salloc((size_t)M_ALL * CMID_ * 4);              // 5.9 MB
    double* W2d    = (double*)salloc((size_t)45 * 512 * 8);
    double* bias2d = (double*)salloc((size_t)45 * 8);
    double* od_d   = (double*)salloc((size_t)M_ALL * 45 * 8);                // 1.0 MB
    float4* boxes  = (float4*)salloc((size_t)NBATCH * NANCH * 16);           // 0.42 MB
    u64*    keys   = (u64*)salloc((size_t)NBATCH * SORTN * 8);               // 0.26 MB
    float4* top    = (float4*)salloc((size_t)NBATCH * PRE_NMS_ * 16);        // 0.19 MB
    u64*    sup    = (u64*)salloc((size_t)NBATCH * PRE_NMS_ * NWORDS * 8);   // 9.0 MB
    float*  maps   = (float*)S;   // overlay: 59.4 MB <= scratch total (~54.8 MB+) — fits
    // total ws usage ~ 86 MB

    int n4 = NBATCH * PADP * CIN_ / 4;
    k_fill0<<<(n4 + 255) / 256, 256, 0, stream>>>((float4*)feat_p, n4);
    k_tfeat<<<dim3((NPOS + 31) / 32, CIN_ / 32, NBATCH), dim3(32, 32), 0, stream>>>(features, feat_p);
    k_twrpn<<<dim3(CIN_ / 16, CMID_ / 64), 256, 0, stream>>>(w_rpn, w_t);
    k_buildW2<<<91, 256, 0, stream>>>(w_obj, w_rbox, b_obj, b_rbox, W2d, bias2d);
    k_buildbias<<<(NMAP + 255) / 256, 256, 0, stream>>>(b_cls, b_bbox, bias_c);
    k_conv<<<dim3((M_ALL + CBM - 1) / CBM, CMID_ / CBN), 256, 0, stream>>>(feat_p, w_t, b_rpn, rpn);
    k_objdl<<<M_ALL, 64, 0, stream>>>(rpn, W2d, bias2d, od_d);
    k_decode<<<(NBATCH * SORTN) / 256, 256, 0, stream>>>(od_d, boxes, keys);
    k_sort<<<NBATCH, 1024, 0, stream>>>(keys);
    k_gather<<<(NBATCH * PRE_NMS_ + 255) / 256, 256, 0, stream>>>(keys, boxes, top);
    k_iou<<<(NBATCH * PRE_NMS_ * NWORDS + 3) / 4, 256, 0, stream>>>(top, sup);
    k_scan<<<NBATCH, 64, 0, stream>>>(keys, top, sup, props);
    k_maps<<<dim3((M_ALL + BM - 1) / BM, (NMAP + BN - 1) / BN), 256, 0, stream>>>(feat_p, w_cls, w_bbox, bias_c, maps);
    k_psroi<<<NBATCH * POST_NMS_, 128, 0, stream>>>(props, maps, out);
}

// Round 4
// 2575.666 us; speedup vs baseline: 1.8387x; 1.4289x over previous
//
#include <hip/hip_runtime.h>
#include <math.h>

using u32 = unsigned int;
using u64 = unsigned long long;

typedef __attribute__((ext_vector_type(8))) __bf16 bf16x8;
typedef __attribute__((ext_vector_type(8))) short short8;
typedef __attribute__((ext_vector_type(4))) float f32x4;

#define HF_ 38
#define WF_ 38
#define NPOS (HF_*WF_)        // 1444
#define NBATCH 2
#define M_ALL (NBATCH*NPOS)   // 2888
#define CIN_ 2048
#define CMID_ 512
#define NA 9
#define NANCH (NPOS*NA)       // 12996
#define SORTN 16384
#define PRE_NMS_ 6000
#define POST_NMS_ 1000
#define NWORDS 94             // ceil(6000/64)
#define NCH 105               // 21 cls + 84 bbox
#define NBIN 49
#define NMAP (NBIN*NCH)       // 5145
#define PADP 1600             // 40*40 padded spatial
#define IMGW_ 608.0

// conv tiling
#define CBM 32
#define CBN 64
#define CBK 16
#define KSPLIT 4

// maps MFMA tiling
#define MBM 128
#define MBN 128
#define MBK 32

__device__ __forceinline__ ushort f2bf(float x) {
    u32 u = __float_as_uint(x);
    u32 r = u + 0x7fffu + ((u >> 16) & 1u);
    return (ushort)(r >> 16);
}
__device__ __forceinline__ float bf2f(ushort h) {
    return __uint_as_float(((u32)h) << 16);
}

// ---------------- zero fill (feat_p) ----------------
__global__ void k_fill0(float4* p, int n4) {
    int i = blockIdx.x * 256 + threadIdx.x;
    if (i < n4) p[i] = make_float4(0.f, 0.f, 0.f, 0.f);
}

// ---------------- features (B,C,H,W) -> padded (B,40,40,C) ----------------
__global__ void k_tfeat(const float* __restrict__ feat, float* __restrict__ feat_p) {
    __shared__ float t[32][33];
    int b = blockIdx.z;
    int pb = blockIdx.x * 32, cb = blockIdx.y * 32;
    int tx = threadIdx.x, ty = threadIdx.y;
    int p = pb + tx, c = cb + ty;
    if (p < NPOS) t[ty][tx] = feat[((size_t)b * CIN_ + c) * NPOS + p];
    __syncthreads();
    int p2 = pb + ty, c2 = cb + tx;
    if (p2 < NPOS) {
        int yy = p2 / WF_, xx = p2 % WF_;
        feat_p[((size_t)b * PADP + (yy + 1) * 40 + (xx + 1)) * CIN_ + c2] = t[tx][ty];
    }
}

// ---------------- w_rpn_conv (OC,C,3,3) -> w_t[tap][c][oc] ----------------
__global__ __launch_bounds__(256) void k_twrpn(const float* __restrict__ w, float* __restrict__ w_t) {
    __shared__ float t[64 * 145];
    int cb = blockIdx.x * 16;   // c tile of 16
    int ob = blockIdx.y * 64;   // oc tile of 64
    int tid = threadIdx.x;
#pragma unroll
    for (int j = 0; j < 9; ++j) {
        int fid = tid + j * 256;           // 0..2303 float4 loads
        int oc = fid / 36, q = fid % 36;
        float4 v = *(const float4*)(w + ((size_t)(ob + oc) * CIN_ + cb) * 9 + q * 4);
        t[oc * 145 + q * 4 + 0] = v.x;
        t[oc * 145 + q * 4 + 1] = v.y;
        t[oc * 145 + q * 4 + 2] = v.z;
        t[oc * 145 + q * 4 + 3] = v.w;
    }
    __syncthreads();
#pragma unroll
    for (int j = 0; j < 9; ++j) {
        int fid = tid + j * 256;
        int pair = fid >> 4, l16 = fid & 15;   // pair: 0..143 = c_local*9+tap
        int cl = pair / 9, tap = pair % 9;
        float4 v;
        v.x = t[(l16 * 4 + 0) * 145 + pair];
        v.y = t[(l16 * 4 + 1) * 145 + pair];
        v.z = t[(l16 * 4 + 2) * 145 + pair];
        v.w = t[(l16 * 4 + 3) * 145 + pair];
        *(float4*)(w_t + ((size_t)tap * CIN_ + cb + cl) * CMID_ + ob + l16 * 4) = v;
    }
}

// ---------------- combine w_obj + w_rpn_box -> W2d[45][512] (f64), bias2d[45] ----------------
__global__ void k_buildW2(const float* __restrict__ w_obj, const float* __restrict__ w_rbox,
                          const float* __restrict__ b_obj, const float* __restrict__ b_rbox,
                          double* __restrict__ W2d, double* __restrict__ bias2d) {
    int idx = blockIdx.x * 256 + threadIdx.x;
    if (idx < 45 * 512) {
        int n = idx >> 9, k = idx & 511;
        W2d[idx] = (double)((n < 9) ? w_obj[n * 512 + k] : w_rbox[(n - 9) * 512 + k]);
    }
    if (idx < 45) bias2d[idx] = (double)((idx < 9) ? b_obj[idx] : b_rbox[idx - 9]);
}

// ---------------- combined psroi bias: bias_c[bin*105+ch] ----------------
__global__ void k_buildbias(const float* __restrict__ b_cls, const float* __restrict__ b_bbox,
                            float* __restrict__ bias_c) {
    int n = blockIdx.x * 256 + threadIdx.x;
    if (n >= NMAP) return;
    int bin = n / NCH, ch = n % NCH;
    bias_c[n] = (ch < 21) ? b_cls[ch * NBIN + bin] : b_bbox[(ch - 21) * NBIN + bin];
}

// ---------------- RPN 3x3 conv, K-split x4: f32 FMA inner, f64 fold, f32 partial ----------------
__global__ __launch_bounds__(256) void k_conv(const float* __restrict__ feat_p,
                                              const float* __restrict__ w_t,
                                              float* __restrict__ part) {
    __shared__ float As[CBK][CBM + 4];
    __shared__ float Bs[CBK][CBN + 4];
    int m0 = blockIdx.x * CBM, n0 = blockIdx.y * CBN;
    int s = blockIdx.z;                 // K-split 0..3, covers k in [s*512, s*512+512) per tap
    int kbeg = s * 512, kend = kbeg + 512;
    int tid = threadIdx.x;
    int tx = tid & 15;
    int tyy = tid >> 4;
    int a_m = tid >> 3, a_k = (tid & 7) * 2;
    int b_k = tid >> 4, b_n = (tid & 15) * 4;
    int gm = m0 + a_m;
    bool mvalid = gm < M_ALL;
    int gms = mvalid ? gm : 0;
    int bb = gms / NPOS, p = gms % NPOS;
    int yy = p / WF_, xx = p % WF_;
    float acc[2][4] = {};
    double accd[2][4] = {};
    int tcount = 0;
    for (int tap = 0; tap < 9; ++tap) {
        int dy = tap / 3 - 1, dx = tap % 3 - 1;
        const float* arow = feat_p + ((size_t)bb * PADP + (yy + dy + 1) * 40 + (xx + dx + 1)) * CIN_;
        const float* brow = w_t + ((size_t)tap * CIN_ + b_k) * CMID_ + n0 + b_n;
        for (int k0 = kbeg; k0 < kend; k0 += CBK) {
            __syncthreads();
            float2 av = make_float2(0.f, 0.f);
            if (mvalid) av = *(const float2*)(arow + k0 + a_k);
            As[a_k + 0][a_m] = av.x;
            As[a_k + 1][a_m] = av.y;
            float4 bv = *(const float4*)(brow + (size_t)k0 * CMID_);
            *(float4*)&Bs[b_k][b_n] = bv;
            __syncthreads();
#pragma unroll
            for (int kk = 0; kk < CBK; ++kk) {
                float a0 = As[kk][tyy * 2 + 0];
                float a1 = As[kk][tyy * 2 + 1];
                float4 b4 = *(const float4*)&Bs[kk][tx * 4];
                acc[0][0] += a0 * b4.x; acc[0][1] += a0 * b4.y;
                acc[0][2] += a0 * b4.z; acc[0][3] += a0 * b4.w;
                acc[1][0] += a1 * b4.x; acc[1][1] += a1 * b4.y;
                acc[1][2] += a1 * b4.z; acc[1][3] += a1 * b4.w;
            }
            if ((++tcount & 3) == 0) {
#pragma unroll
                for (int i2 = 0; i2 < 2; ++i2)
#pragma unroll
                    for (int j2 = 0; j2 < 4; ++j2) {
                        accd[i2][j2] += (double)acc[i2][j2];
                        acc[i2][j2] = 0.f;
                    }
            }
        }
    }
#pragma unroll
    for (int i2 = 0; i2 < 2; ++i2)
#pragma unroll
        for (int j2 = 0; j2 < 4; ++j2) accd[i2][j2] += (double)acc[i2][j2];
#pragma unroll
    for (int i2 = 0; i2 < 2; ++i2) {
        int gmm = m0 + tyy * 2 + i2;
        if (gmm >= M_ALL) continue;
        int gn = n0 + tx * 4;
        float4 o;
        o.x = (float)accd[i2][0];
        o.y = (float)accd[i2][1];
        o.z = (float)accd[i2][2];
        o.w = (float)accd[i2][3];
        *(float4*)(part + ((size_t)s * M_ALL + gmm) * CMID_ + gn) = o;
    }
}

// ---------------- combine conv partials (fixed f64 order) + bias + relu ----------------
__global__ void k_cmb(const float* __restrict__ part, const float* __restrict__ bias,
                      float* __restrict__ rpn) {
    int i = blockIdx.x * 256 + threadIdx.x;
    if (i >= M_ALL * CMID_) return;
    int n = i & (CMID_ - 1);
    const size_t MN = (size_t)M_ALL * CMID_;
    double v = (double)part[i] + (double)part[MN + i] + (double)part[2 * MN + i] + (double)part[3 * MN + i]
             + (double)bias[n];
    rpn[i] = (float)fmax(v, 0.0);
}

// ---------------- obj + deltas 1x1 (f64 accumulate from f32 rpn): od_d[m][45] ----------------
__global__ __launch_bounds__(64) void k_objdl(const float* __restrict__ rpn,
                                              const double* __restrict__ W2d,
                                              const double* __restrict__ bias2d,
                                              double* __restrict__ od_d) {
    __shared__ float s[512];
    int m = blockIdx.x;
    int tid = threadIdx.x;
    for (int i = tid; i < 512; i += 64) s[i] = rpn[(size_t)m * 512 + i];
    __syncthreads();
    if (tid < 45) {
        double acc = 0.0;
        for (int k = 0; k < 512; ++k) acc += (double)s[k] * W2d[tid * 512 + k];
        od_d[(size_t)m * 45 + tid] = acc + bias2d[tid];
    }
}

// ---------------- decode boxes (f64 truth, f32 data semantics) + sort keys ----------------
__global__ void k_decode(const double* __restrict__ od_d, float4* __restrict__ boxes, u64* __restrict__ keys) {
    int g = blockIdx.x * 256 + threadIdx.x;
    if (g >= NBATCH * SORTN) return;
    int b = g / SORTN, i = g % SORTN;
    if (i >= NANCH) { keys[(size_t)b * SORTN + i] = ~0ull; return; }
    int p = i / NA, a = i % NA;
    int yy = p / WF_, xx = p % WF_;
    int ri = a / 3, si = a % 3;
    double sq = (ri == 0) ? 0.70710678118654757 : ((ri == 1) ? 1.0 : 1.4142135623730951);
    double size = 16.0 * (double)(8 << si);
    float wsa = (float)(size / sq);
    float hsa = (float)(size * sq);
    float cx = (xx + 0.5f) * 16.f, cy = (yy + 0.5f) * 16.f;
    float x1a = cx - 0.5f * wsa, x2a = cx + 0.5f * wsa;
    float y1a = cy - 0.5f * hsa, y2a = cy + 0.5f * hsa;
    float wa = x2a - x1a, ha = y2a - y1a;
    float cxa = x1a + 0.5f * wa, cya = y1a + 0.5f * ha;
    const double* dptr = od_d + (size_t)(b * NPOS + p) * 45;
    double obj = dptr[a];
    double d0 = dptr[9 + a * 4 + 0], d1 = dptr[9 + a * 4 + 1];
    double d2 = dptr[9 + a * 4 + 2], d3 = dptr[9 + a * 4 + 3];
    double ncx = (double)cxa + d0 * (double)wa;
    double ncy = (double)cya + d1 * (double)ha;
    double nw = (double)wa * exp(fmin(fmax(d2, -4.0), 4.0));
    double nh = (double)ha * exp(fmin(fmax(d3, -4.0), 4.0));
    float x1 = (float)fmin(fmax(ncx - 0.5 * nw, 0.0), IMGW_);
    float y1 = (float)fmin(fmax(ncy - 0.5 * nh, 0.0), IMGW_);
    float x2 = (float)fmin(fmax(ncx + 0.5 * nw, 0.0), IMGW_);
    float y2 = (float)fmin(fmax(ncy + 0.5 * nh, 0.0), IMGW_);
    boxes[(size_t)b * NANCH + i] = make_float4(x1, y1, x2, y2);
    float w = x2 - x1, h = y2 - y1;
    float score = (w >= 16.f && h >= 16.f) ? (float)obj : -INFINITY;
    u32 f = __float_as_uint(score);
    u32 mk = (f & 0x80000000u) ? ~f : (f | 0x80000000u);
    u32 d = ~mk;
    keys[(size_t)b * SORTN + i] = ((u64)d << 32) | (u32)i;
}

// ---------------- single-block bitonic sort in LDS (per batch) over 16384 u64 keys ----------------
__global__ __launch_bounds__(1024) void k_sort(u64* __restrict__ keys) {
    __shared__ u64 lk[SORTN];      // 128 KB
    u64* kg = keys + (size_t)blockIdx.x * SORTN;
    int tid = threadIdx.x;
    for (int i = tid; i < SORTN; i += 1024) lk[i] = kg[i];
    for (int size = 2; size <= SORTN; size <<= 1) {
        for (int stride = size >> 1; stride > 0; stride >>= 1) {
            __syncthreads();
#pragma unroll
            for (int r = 0; r < 8; ++r) {
                int t = tid + r * 1024;
                int i = ((t & ~(stride - 1)) << 1) | (t & (stride - 1));
                int j = i | stride;
                bool up = ((i & size) == 0);
                u64 a = lk[i], b = lk[j];
                if ((a > b) == up) { lk[i] = b; lk[j] = a; }
            }
        }
    }
    __syncthreads();
    for (int i = tid; i < SORTN; i += 1024) kg[i] = lk[i];
}

// ---------------- gather top 6000 boxes in sorted order ----------------
__global__ void k_gather(const u64* __restrict__ keys, const float4* __restrict__ boxes,
                         float4* __restrict__ top) {
    int g = blockIdx.x * 256 + threadIdx.x;
    if (g >= NBATCH * PRE_NMS_) return;
    int b = g / PRE_NMS_, j = g % PRE_NMS_;
    u32 idx = (u32)keys[(size_t)b * SORTN + j];
    if (idx >= NANCH) idx = 0;
    top[(size_t)b * PRE_NMS_ + j] = boxes[(size_t)b * NANCH + idx];
}

// ---------------- pairwise suppression bit matrix (f32, reference op order) ----------------
__global__ __launch_bounds__(256) void k_iou(const float4* __restrict__ top, u64* __restrict__ sup) {
    int wid = blockIdx.x * 4 + (threadIdx.x >> 6);
    int lane = threadIdx.x & 63;
    if (wid >= NBATCH * PRE_NMS_ * NWORDS) return;
    int b = wid / (PRE_NMS_ * NWORDS);
    int rem = wid % (PRE_NMS_ * NWORDS);
    int i = rem / NWORDS, wj = rem % NWORDS;
    const float4* tb = top + (size_t)b * PRE_NMS_;
    float4 bi = tb[i];
    int j = wj * 64 + lane;
    bool s = false;
    if (j < PRE_NMS_) {
        float4 bj = tb[j];
        float xx1 = fmaxf(bi.x, bj.x), yy1 = fmaxf(bi.y, bj.y);
        float xx2 = fminf(bi.z, bj.z), yy2 = fminf(bi.w, bj.w);
        float inter = fmaxf(xx2 - xx1, 0.f) * fmaxf(yy2 - yy1, 0.f);
        float ai = (bi.z - bi.x) * (bi.w - bi.y);
        float aj = (bj.z - bj.x) * (bj.w - bj.y);
        float iou = inter / (ai + aj - inter + 1e-9f);
        s = iou > 0.7f;
    }
    u64 mask = __ballot(s);
    if (lane == 0) sup[(size_t)wid] = mask;
}

// ---------------- sequential NMS scan (1 wave per batch, bitmask in registers) ----------------
__global__ void k_scan(const u64* __restrict__ keys, const float4* __restrict__ top,
                       const u64* __restrict__ sup, float4* __restrict__ props) {
    int b = blockIdx.x;
    int lane = threadIdx.x;
    const u64* kk = keys + (size_t)b * SORTN;
    const float4* tb = top + (size_t)b * PRE_NMS_;
    const u64* mat = sup + (size_t)b * PRE_NMS_ * NWORDS;
    float4* pr = props + (size_t)b * POST_NMS_;
    int lo = 0, hi = PRE_NMS_;
    while (lo < hi) {
        int mid = (lo + hi) >> 1;
        u32 khi = (u32)(kk[mid] >> 32);
        if (khi < 0xFF800000u) lo = mid + 1; else hi = mid;
    }
    int limit = lo;
    u64 r0 = 0, r1 = 0;
    int kept = 0;
    for (int i = 0; i < limit && kept < POST_NMS_; ++i) {
        int w = i >> 6, bit = i & 63;
        u64 word = (w < 64) ? __shfl(r0, w) : __shfl(r1, w - 64);
        if (!((word >> bit) & 1ull)) {
            if (lane == 0) pr[kept] = tb[i];
            const u64* row = mat + (size_t)i * NWORDS;
            r0 |= row[lane];
            int w1 = lane + 64;
            if (w1 < NWORDS) r1 |= row[w1];
            kept++;
        }
    }
    float4 pad = tb[0];
    for (int q = kept + lane; q < POST_NMS_; q += 64) pr[q] = pad;
}

// ---------------- split feat_p (f32, padded) -> bf16 hi/lo planes [m][2048] ----------------
__global__ void k_split_feat(const float* __restrict__ feat_p,
                             ushort* __restrict__ Fh, ushort* __restrict__ Fl) {
    int g = blockIdx.x * 256 + threadIdx.x;
    if (g >= M_ALL * CIN_ / 8) return;
    size_t idx = (size_t)g * 8;
    int m = (int)(idx >> 11), k = (int)(idx & 2047);
    int bb = m / NPOS, p = m % NPOS;
    int yy = p / WF_, xx = p % WF_;
    const float* src = feat_p + ((size_t)bb * PADP + (yy + 1) * 40 + (xx + 1)) * CIN_ + k;
    float4 v0 = *(const float4*)(src);
    float4 v1 = *(const float4*)(src + 4);
    float xs[8] = {v0.x, v0.y, v0.z, v0.w, v1.x, v1.y, v1.z, v1.w};
    union { ushort4 v[2]; ushort u[8]; } h, l;
#pragma unroll
    for (int q = 0; q < 8; ++q) {
        ushort hb = f2bf(xs[q]);
        h.u[q] = hb;
        l.u[q] = f2bf(xs[q] - bf2f(hb));
    }
    *(ushort4*)(Fh + idx) = h.v[0];
    *(ushort4*)(Fh + idx + 4) = h.v[1];
    *(ushort4*)(Fl + idx) = l.v[0];
    *(ushort4*)(Fl + idx + 4) = l.v[1];
}

// ---------------- psroi maps GEMM via MFMA bf16x2 (3-pass): maps[m][bin*105+ch] ----------------
__global__ __launch_bounds__(256) void k_maps(const ushort* __restrict__ Fh, const ushort* __restrict__ Fl,
                                              const float* __restrict__ w_cls,
                                              const float* __restrict__ w_bbox,
                                              const float* __restrict__ bias_c,
                                              float* __restrict__ maps) {
    // Each row: 8 chunks of 8 bf16 (16B): chunks 0-3 = hi (k=chunk*8..+8), 4-7 = lo.
    // Physical chunk = logical ^ (row & 7)  (XOR swizzle -> ~2-way banks on b128).
    __shared__ __align__(16) ushort At[MBM][64];
    __shared__ __align__(16) ushort Bt[MBN][64];
    int tid = threadIdx.x;
    int m0 = blockIdx.x * MBM, n0 = blockIdx.y * MBN;
    // staging coords: 2 threads per row, 16 elems each
    int sr = tid >> 1;
    int half = tid & 1;
    int sc = half << 4;
    int skey = sr & 7;
    int gm = m0 + sr;
    const ushort* fhp = nullptr; const ushort* flp = nullptr;
    if (gm < M_ALL) {
        fhp = Fh + (size_t)gm * CIN_ + sc;
        flp = Fl + (size_t)gm * CIN_ + sc;
    }
    int gn = n0 + sr;
    const float* wp = nullptr;
    if (gn < NMAP) {
        int bin = gn / NCH, ch = gn % NCH;
        wp = (ch < 21) ? w_cls + (size_t)(ch * NBIN + bin) * CIN_ + sc
                       : w_bbox + (size_t)((ch - 21) * NBIN + bin) * CIN_ + sc;
    }
    // wave/frag coords
    int wv = tid >> 6;
    int wm = (wv >> 1) * 64, wn = (wv & 1) * 64;
    int lane = tid & 63;
    int r16 = lane & 15;
    int kg = lane >> 4;                 // frag k chunk (8 bf16)
    int key = r16 & 7;
    f32x4 acc[4][4] = {};
    const short8 z8 = {0, 0, 0, 0, 0, 0, 0, 0};

    for (int k0 = 0; k0 < CIN_; k0 += MBK) {
        __syncthreads();
        // ---- stage A (bf16 planes, direct) ----
        {
            short8 a0 = z8, a1 = z8, l0 = z8, l1 = z8;
            if (fhp) {
                a0 = *(const short8*)(fhp + k0);
                a1 = *(const short8*)(fhp + k0 + 8);
                l0 = *(const short8*)(flp + k0);
                l1 = *(const short8*)(flp + k0 + 8);
            }
            int c0 = 2 * half, c1 = 2 * half + 1;
            *(short8*)&At[sr][(c0 ^ skey) * 8] = a0;
            *(short8*)&At[sr][(c1 ^ skey) * 8] = a1;
            *(short8*)&At[sr][((4 + c0) ^ skey) * 8] = l0;
            *(short8*)&At[sr][((4 + c1) ^ skey) * 8] = l1;
        }
        // ---- stage B (split f32 weights in-kernel) ----
        {
            union { short8 v; ushort u[8]; } h0, h1, l0, l1;
            h0.v = z8; h1.v = z8; l0.v = z8; l1.v = z8;
            if (wp) {
                float4 w0 = *(const float4*)(wp + k0);
                float4 w1 = *(const float4*)(wp + k0 + 4);
                float4 w2 = *(const float4*)(wp + k0 + 8);
                float4 w3 = *(const float4*)(wp + k0 + 12);
                float xs[16] = {w0.x, w0.y, w0.z, w0.w, w1.x, w1.y, w1.z, w1.w,
                                w2.x, w2.y, w2.z, w2.w, w3.x, w3.y, w3.z, w3.w};
#pragma unroll
                for (int q = 0; q < 8; ++q) {
                    ushort hb = f2bf(xs[q]);
                    h0.u[q] = hb;
                    l0.u[q] = f2bf(xs[q] - bf2f(hb));
                }
#pragma unroll
                for (int q = 0; q < 8; ++q) {
                    ushort hb = f2bf(xs[8 + q]);
                    h1.u[q] = hb;
                    l1.u[q] = f2bf(xs[8 + q] - bf2f(hb));
                }
            }
            int c0 = 2 * half, c1 = 2 * half + 1;
            *(short8*)&Bt[sr][(c0 ^ skey) * 8] = h0.v;
            *(short8*)&Bt[sr][(c1 ^ skey) * 8] = h1.v;
            *(short8*)&Bt[sr][((4 + c0) ^ skey) * 8] = l0.v;
            *(short8*)&Bt[sr][((4 + c1) ^ skey) * 8] = l1.v;
        }
        __syncthreads();
        // ---- fragments + MFMA ----
        bf16x8 afh[4], afl[4], bfh[4], bfl[4];
#pragma unroll
        for (int mi = 0; mi < 4; ++mi) {
            const ushort* rp = &At[wm + mi * 16 + r16][0];
            afh[mi] = *(const bf16x8*)(rp + ((kg ^ key) * 8));
            afl[mi] = *(const bf16x8*)(rp + (((4 + kg) ^ key) * 8));
        }
#pragma unroll
        for (int ni = 0; ni < 4; ++ni) {
            const ushort* rp = &Bt[wn + ni * 16 + r16][0];
            bfh[ni] = *(const bf16x8*)(rp + ((kg ^ key) * 8));
            bfl[ni] = *(const bf16x8*)(rp + (((4 + kg) ^ key) * 8));
        }
#pragma unroll
        for (int mi = 0; mi < 4; ++mi)
#pragma unroll
            for (int ni = 0; ni < 4; ++ni) {
                acc[mi][ni] = __builtin_amdgcn_mfma_f32_16x16x32_bf16(afh[mi], bfh[ni], acc[mi][ni], 0, 0, 0);
                acc[mi][ni] = __builtin_amdgcn_mfma_f32_16x16x32_bf16(afh[mi], bfl[ni], acc[mi][ni], 0, 0, 0);
                acc[mi][ni] = __builtin_amdgcn_mfma_f32_16x16x32_bf16(afl[mi], bfh[ni], acc[mi][ni], 0, 0, 0);
            }
    }
    // ---- epilogue: D row=(l>>4)*4+j, col=l&15 (m89-verified) ----
#pragma unroll
    for (int mi = 0; mi < 4; ++mi) {
#pragma unroll
        for (int ni = 0; ni < 4; ++ni) {
            int col = n0 + wn + ni * 16 + r16;
            if (col >= NMAP) continue;
            float bc = bias_c[col];
#pragma unroll
            for (int j = 0; j < 4; ++j) {
                int row = m0 + wm + mi * 16 + kg * 4 + j;
                if (row < M_ALL) maps[(size_t)row * NMAP + col] = acc[mi][ni][j] + bc;
            }
        }
    }
}

// ---------------- psroi align + mean (4-way ILP) ----------------
__global__ __launch_bounds__(128) void k_psroi(const float4* __restrict__ props,
                                               const float* __restrict__ maps,
                                               float* __restrict__ out) {
    __shared__ int so[4][196];
    __shared__ float sw[4][196];
    int r = blockIdx.x;
    int b = r / POST_NMS_;
    int tid = threadIdx.x;
    float4 box = props[r];
    float x1 = box.x * 0.0625f, y1 = box.y * 0.0625f;
    float bw = fmaxf(box.z * 0.0625f - x1, 1.f) / 7.f;
    float bh = fmaxf(box.w * 0.0625f - y1, 1.f) / 7.f;
    for (int s = tid; s < 196; s += 128) {
        int bin = s >> 2, sy = (s >> 1) & 1, sx = s & 1;
        int ph = bin / 7, pw = bin % 7;
        float gx = (float)pw + (sx ? 0.75f : 0.25f);
        float gy = (float)ph + (sy ? 0.75f : 0.25f);
        float px = fminf(fmaxf(x1 + gx * bw, 0.f), 37.f);
        float py = fminf(fmaxf(y1 + gy * bh, 0.f), 37.f);
        float x0f = floorf(px), y0f = floorf(py);
        float lx = px - x0f, ly = py - y0f;
        int x0 = (int)x0f, y0 = (int)y0f;
        int x1i = min(x0 + 1, 37), y1i = min(y0 + 1, 37);
        int base = b * NPOS;
        so[0][s] = (base + y0 * WF_ + x0) * NMAP + bin * NCH;
        so[1][s] = (base + y0 * WF_ + x1i) * NMAP + bin * NCH;
        so[2][s] = (base + y1i * WF_ + x0) * NMAP + bin * NCH;
        so[3][s] = (base + y1i * WF_ + x1i) * NMAP + bin * NCH;
        sw[0][s] = (1.f - ly) * (1.f - lx);
        sw[1][s] = (1.f - ly) * lx;
        sw[2][s] = ly * (1.f - lx);
        sw[3][s] = ly * lx;
    }
    __syncthreads();
    if (tid < NCH) {
        float a0 = 0.f, a1 = 0.f, a2 = 0.f, a3 = 0.f;
        for (int s = 0; s < 196; s += 4) {
            a0 += sw[0][s] * maps[(size_t)(so[0][s] + tid)]
                + sw[1][s] * maps[(size_t)(so[1][s] + tid)]
                + sw[2][s] * maps[(size_t)(so[2][s] + tid)]
                + sw[3][s] * maps[(size_t)(so[3][s] + tid)];
            a1 += sw[0][s+1] * maps[(size_t)(so[0][s+1] + tid)]
                + sw[1][s+1] * maps[(size_t)(so[1][s+1] + tid)]
                + sw[2][s+1] * maps[(size_t)(so[2][s+1] + tid)]
                + sw[3][s+1] * maps[(size_t)(so[3][s+1] + tid)];
            a2 += sw[0][s+2] * maps[(size_t)(so[0][s+2] + tid)]
                + sw[1][s+2] * maps[(size_t)(so[1][s+2] + tid)]
                + sw[2][s+2] * maps[(size_t)(so[2][s+2] + tid)]
                + sw[3][s+2] * maps[(size_t)(so[3][s+2] + tid)];
            a3 += sw[0][s+3] * maps[(size_t)(so[0][s+3] + tid)]
                + sw[1][s+3] * maps[(size_t)(so[1][s+3] + tid)]
                + sw[2][s+3] * maps[(size_t)(so[2][s+3] + tid)]
                + sw[3][s+3] * maps[(size_t)(so[3][s+3] + tid)];
        }
        out[(size_t)r * NCH + tid] = ((a0 + a1) + (a2 + a3)) * 0.25f / 49.f;
    }
}

extern "C" void kernel_launch(void* const* d_in, const int* in_sizes, int n_in,
                              void* d_out, int out_size, void* d_ws, size_t ws_size,
                              hipStream_t stream) {
    (void)in_sizes; (void)n_in; (void)out_size; (void)ws_size;
    const float* features = (const float*)d_in[0];
    const float* w_rpn    = (const float*)d_in[1];
    const float* b_rpn    = (const float*)d_in[2];
    const float* w_obj    = (const float*)d_in[3];
    const float* b_obj    = (const float*)d_in[4];
    const float* w_rbox   = (const float*)d_in[5];
    const float* b_rbox   = (const float*)d_in[6];
    const float* w_cls    = (const float*)d_in[7];
    const float* b_cls    = (const float*)d_in[8];
    const float* w_bbox   = (const float*)d_in[9];
    const float* b_bbox   = (const float*)d_in[10];
    float* out = (float*)d_out;

    char* ws = (char*)d_ws;
    size_t off = 0;
    auto alloc = [&](size_t bytes) -> char* {
        char* p = ws + off;
        off += (bytes + 255) & ~(size_t)255;
        return p;
    };
    // persistent region (~26.3 MB)
    float*  feat_p = (float*)alloc((size_t)NBATCH * PADP * CIN_ * 4);
    float4* props  = (float4*)alloc((size_t)NBATCH * POST_NMS_ * 16);
    float*  bias_c = (float*)alloc((size_t)NMAP * 4);
    // S0: w_t (37.75 MB); later overlaid by Fh/Fl bf16 planes (23.7 MB)
    char* S0 = alloc((size_t)9 * CIN_ * CMID_ * 4);
    float*  w_t = (float*)S0;
    ushort* Fh  = (ushort*)S0;
    ushort* Fl  = Fh + (size_t)M_ALL * CIN_;
    // S1: RPN/NMS scratch; later overlaid entirely by maps (59.45 MB)
    size_t s1_need = 0;
    {
        size_t t = 0;
        t += ((size_t)KSPLIT * M_ALL * CMID_ * 4 + 255) & ~(size_t)255;   // part 23.66
        t += ((size_t)M_ALL * CMID_ * 4 + 255) & ~(size_t)255;            // rpn 5.92
        t += ((size_t)45 * 512 * 8 + 255) & ~(size_t)255;                 // W2d
        t += ((size_t)45 * 8 + 255) & ~(size_t)255;                       // bias2d
        t += ((size_t)M_ALL * 45 * 8 + 255) & ~(size_t)255;               // od_d
        t += ((size_t)NBATCH * NANCH * 16 + 255) & ~(size_t)255;          // boxes
        t += ((size_t)NBATCH * SORTN * 8 + 255) & ~(size_t)255;           // keys
        t += ((size_t)NBATCH * PRE_NMS_ * 16 + 255) & ~(size_t)255;       // top
        t += ((size_t)NBATCH * PRE_NMS_ * NWORDS * 8 + 255) & ~(size_t)255; // sup
        size_t mapsz = (size_t)M_ALL * NMAP * 4;
        s1_need = t > mapsz ? t : mapsz;
    }
    char* S1 = alloc(s1_need);
    size_t soff = 0;
    auto salloc = [&](size_t bytes) -> char* {
        char* p = S1 + soff;
        soff += (bytes + 255) & ~(size_t)255;
        return p;
    };
    float*  part   = (float*)salloc((size_t)KSPLIT * M_ALL * CMID_ * 4);
    float*  rpn    = (float*)salloc((size_t)M_ALL * CMID_ * 4);
    double* W2d    = (double*)salloc((size_t)45 * 512 * 8);
    double* bias2d = (double*)salloc((size_t)45 * 8);
    double* od_d   = (double*)salloc((size_t)M_ALL * 45 * 8);
    float4* boxes  = (float4*)salloc((size_t)NBATCH * NANCH * 16);
    u64*    keys   = (u64*)salloc((size_t)NBATCH * SORTN * 8);
    float4* top    = (float4*)salloc((size_t)NBATCH * PRE_NMS_ * 16);
    u64*    sup    = (u64*)salloc((size_t)NBATCH * PRE_NMS_ * NWORDS * 8);
    float*  maps   = (float*)S1;   // overlay after k_scan
    // total ws ~ 124 MB

    int n4 = NBATCH * PADP * CIN_ / 4;
    k_fill0<<<(n4 + 255) / 256, 256, 0, stream>>>((float4*)feat_p, n4);
    k_tfeat<<<dim3((NPOS + 31) / 32, CIN_ / 32, NBATCH), dim3(32, 32), 0, stream>>>(features, feat_p);
    k_twrpn<<<dim3(CIN_ / 16, CMID_ / 64), 256, 0, stream>>>(w_rpn, w_t);
    k_buildW2<<<91, 256, 0, stream>>>(w_obj, w_rbox, b_obj, b_rbox, W2d, bias2d);
    k_buildbias<<<(NMAP + 255) / 256, 256, 0, stream>>>(b_cls, b_bbox, bias_c);
    k_conv<<<dim3((M_ALL + CBM - 1) / CBM, CMID_ / CBN, KSPLIT), 256, 0, stream>>>(feat_p, w_t, part);
    k_cmb<<<(M_ALL * CMID_ + 255) / 256, 256, 0, stream>>>(part, b_rpn, rpn);
    k_objdl<<<M_ALL, 64, 0, stream>>>(rpn, W2d, bias2d, od_d);
    k_split_feat<<<(M_ALL * CIN_ / 8 + 255) / 256, 256, 0, stream>>>(feat_p, Fh, Fl);
    k_decode<<<(NBATCH * SORTN) / 256, 256, 0, stream>>>(od_d, boxes, keys);
    k_sort<<<NBATCH, 1024, 0, stream>>>(keys);
    k_gather<<<(NBATCH * PRE_NMS_ + 255) / 256, 256, 0, stream>>>(keys, boxes, top);
    k_iou<<<(NBATCH * PRE_NMS_ * NWORDS + 3) / 4, 256, 0, stream>>>(top, sup);
    k_scan<<<NBATCH, 64, 0, stream>>>(keys, top, sup, props);
    k_maps<<<dim3((M_ALL + MBM - 1) / MBM, (NMAP + MBN - 1) / MBN), 256, 0, stream>>>(Fh, Fl, w_cls, w_bbox, bias_c, maps);
    k_psroi<<<NBATCH * POST_NMS_, 128, 0, stream>>>(props, maps, out);
}